// Round 22
// baseline (126.595 us; speedup 1.0000x reference)
//
#include <hip/hip_runtime.h>
#include <math.h>

// ---------------------------------------------------------------------------
// MultiHeadAttention forward, MI355X/gfx950.  Round 22.
//   pack_all: fused fp32->bf16 (one launch, HBM roofline)
//   gemm_qkv: R13 core + NEW coalesced epilogue: C-tile bounced through a
//     padded LDS buffer ([row][col] for z<2, [col][row] for z=2) so stores
//     go out as 256B-contiguous 16B/lane chunks instead of scattered 2B
//     scalars (z=2's old path: 2B at 4KB stride).  Values bit-identical.
//   gemm_out: R13-exact 64x128 dbuf + T2 swizzle
//   attn_fwd: R19-exact (58us: defer-max + branch-local shuffles)
// ---------------------------------------------------------------------------

typedef __attribute__((ext_vector_type(8))) short short8;     // 8 x bf16 frag
typedef __attribute__((ext_vector_type(4))) float f32x4;      // MFMA acc
typedef __attribute__((ext_vector_type(4))) float float4v;
typedef __attribute__((ext_vector_type(4))) unsigned short ushort4v;
typedef __attribute__((ext_vector_type(2))) unsigned int uint2v;

typedef __attribute__((address_space(3))) unsigned int lds_uint;
typedef __attribute__((address_space(1))) unsigned int glb_uint;

__device__ __forceinline__ void gload_lds16(const void* g, void* l) {
    __builtin_amdgcn_global_load_lds((glb_uint*)(unsigned long long)g,
                                     (lds_uint*)(unsigned int)(unsigned long long)l,
                                     16, 0, 0);
}

__device__ __forceinline__ unsigned short f32_bf16(float f) {
    union { float f; unsigned int u; } x; x.f = f;
    unsigned int r = x.u + 0x7fffu + ((x.u >> 16) & 1u);   // RNE
    return (unsigned short)(r >> 16);
}

__device__ __forceinline__ unsigned int cvt_pk_bf16(float lo, float hi) {
    unsigned int r;
    asm("v_cvt_pk_bf16_f32 %0, %1, %2" : "=v"(r) : "v"(lo), "v"(hi));
    return r;
}

// single-instruction exp2
__device__ __forceinline__ float exp2_fast(float x) {
    float r;
    asm("v_exp_f32 %0, %1" : "=v"(r) : "v"(x));
    return r;
}

// SCALE * log2(e): folded into Q projection so softmax runs in exp2 domain
#define QSCALE 0.18033688011112042f

// ---------------------------------------------------------------------------
// Fused pack: blocks 0..12287 -> q/k/v; blocks 12288..16383 -> weights.
__global__ void pack_all(const float* __restrict__ q, const float* __restrict__ k,
                         const float* __restrict__ v,
                         const float* __restrict__ wq, const float* __restrict__ wk,
                         const float* __restrict__ wv, const float* __restrict__ wo,
                         unsigned short* __restrict__ oq, unsigned short* __restrict__ ok,
                         unsigned short* __restrict__ ov,
                         unsigned short* __restrict__ owq, unsigned short* __restrict__ owk,
                         unsigned short* __restrict__ owv, unsigned short* __restrict__ owo)
{
    const int blk = blockIdx.x;
    const float* in;
    unsigned short* out;
    int i;
    if (blk < 12288) {                       // q/k/v: 4096 blocks each
        const int sel = blk >> 12;           // 0,1,2
        in  = (sel == 0) ? q : (sel == 1) ? k : v;
        out = (sel == 0) ? oq : (sel == 1) ? ok : ov;
        i = ((blk & 4095) << 8) + threadIdx.x;
    } else {                                 // weights: 1024 blocks each
        const int wb = blk - 12288;
        const int sel = wb >> 10;            // 0..3
        in  = (sel == 0) ? wq : (sel == 1) ? wk : (sel == 2) ? wv : wo;
        out = (sel == 0) ? owq : (sel == 1) ? owk : (sel == 2) ? owv : owo;
        i = ((wb & 1023) << 8) + threadIdx.x;
    }
    float4v vv = ((const float4v*)in)[i];
    ushort4v o;
    o.x = f32_bf16(vv.x); o.y = f32_bf16(vv.y);
    o.z = f32_bf16(vv.z); o.w = f32_bf16(vv.w);
    ((ushort4v*)out)[i] = o;
}

// ---------------------------------------------------------------------------
// Batched QKV projection GEMM.  R13 core (128x128, 4 waves, T2 swizzle) +
// coalesced LDS-bounce epilogue.  LDS: As 16K + Bs 16K + T 34.8K = 66.8KB
// -> still 2 blocks/CU under (256,2).
__global__ __launch_bounds__(256, 2) void gemm_qkv(
    const unsigned short* __restrict__ A0, const unsigned short* __restrict__ A1,
    const unsigned short* __restrict__ A2,
    const unsigned short* __restrict__ W0, const unsigned short* __restrict__ W1,
    const unsigned short* __restrict__ W2,
    const float* __restrict__ bs0, const float* __restrict__ bs1,
    const float* __restrict__ bs2,
    unsigned short* __restrict__ O0, unsigned short* __restrict__ O1,
    unsigned short* __restrict__ O2)
{
    const int z = blockIdx.z;
    const unsigned short* A = (z == 0) ? A0 : (z == 1) ? A1 : A2;
    const unsigned short* W = (z == 0) ? W0 : (z == 1) ? W1 : W2;
    const float* bias        = (z == 0) ? bs0 : (z == 1) ? bs1 : bs2;
    unsigned short* C        = (z == 0) ? O0 : (z == 1) ? O1 : O2;
    const float oscale = (z == 0) ? QSCALE : 1.0f;
    const int N = 1024, K = 1024;

    __shared__ unsigned short As[128 * 64];
    __shared__ unsigned short Bs[128 * 64];
    __shared__ unsigned short T[128 * 136];     // C-tile bounce (pad 136:
                                                // 16B-aligned rows, 2-way banks)
    const int tid  = threadIdx.x;
    const int lane = tid & 63, wave = tid >> 6;
    const int l15 = lane & 15, l4 = lane >> 4;
    const int bm = blockIdx.y * 128, bn = blockIdx.x * 128;
    const int wr = wave >> 1, wc = wave & 1;
    const int swz = l15 & 7;                    // XOR key (8-short units)

    f32x4 acc[4][4];
    #pragma unroll
    for (int i = 0; i < 4; ++i)
        #pragma unroll
        for (int j = 0; j < 4; ++j)
            #pragma unroll
            for (int e = 0; e < 4; ++e) acc[i][j][e] = 0.f;

    const int srow = lane >> 3;                 // row 0..7 within chunk
    const int scol = ((lane & 7) ^ srow) * 8;   // pre-swizzled source col

    for (int k0 = 0; k0 < K; k0 += 64) {
        __syncthreads();
        #pragma unroll
        for (int i = 0; i < 4; ++i) {
            int c = wave * 4 + i;
            int row = c * 8 + srow;
            gload_lds16(A + (size_t)(bm + row) * K + k0 + scol, &As[c * 512]);
            gload_lds16(W + (size_t)(bn + row) * K + k0 + scol, &Bs[c * 512]);
        }
        __syncthreads();
        #pragma unroll
        for (int kk = 0; kk < 2; ++kk) {
            short8 af[4], bf[4];
            const int ko = ((kk * 4 + l4) ^ swz) << 3;   // swizzled col
            #pragma unroll
            for (int i = 0; i < 4; ++i)
                af[i] = *(const short8*)&As[(wr * 64 + i * 16 + l15) * 64 + ko];
            #pragma unroll
            for (int j = 0; j < 4; ++j)
                bf[j] = *(const short8*)&Bs[(wc * 64 + j * 16 + l15) * 64 + ko];
            #pragma unroll
            for (int i = 0; i < 4; ++i)
                #pragma unroll
                for (int j = 0; j < 4; ++j)
                    acc[i][j] = __builtin_amdgcn_mfma_f32_16x16x32_bf16(
                        af[i], bf[j], acc[i][j], 0, 0, 0);
        }
    }

    // ---- epilogue phase 1: bias/scale/convert -> LDS bounce buffer ----
    // z<2: T[row][col] (output contiguous along col); z=2: T[col][row]
    // (vt contiguous along t=row).  Values identical to the old scalar path.
    #pragma unroll
    for (int j = 0; j < 4; ++j) {
        const int cl = wc * 64 + j * 16 + l15;          // col_local
        const float bj = bias[bn + cl];
        #pragma unroll
        for (int i = 0; i < 4; ++i) {
            const int rl0 = wr * 64 + i * 16 + l4 * 4;  // row_local base
            #pragma unroll
            for (int r = 0; r < 4; ++r) {
                const unsigned short bv = f32_bf16((acc[i][j][r] + bj) * oscale);
                if (z < 2) T[(rl0 + r) * 136 + cl] = bv;
                else       T[cl * 136 + rl0 + r]  = bv;
            }
        }
    }
    __syncthreads();

    // ---- epilogue phase 2: 16-lane groups emit 256B-contiguous stores ----
    const int grp = tid >> 4;           // 0..15: row (z<2) / col (z=2) group
    const int sub = (tid & 15) * 8;     // 8-element chunk within 128
    #pragma unroll
    for (int it = 0; it < 8; ++it) {
        const int major = it * 16 + grp;
        const short8 w = *(const short8*)&T[major * 136 + sub];
        if (z < 2) {
            *(short8*)&C[(size_t)(bm + major) * N + bn + sub] = w;
        } else {
            const int colg = bn + major;
            const int b2 = bm >> 11;                    // tile never straddles b
            const size_t vrow = ((size_t)((b2 << 4) + (colg >> 6)) << 6)
                                + (colg & 63);
            *(short8*)&C[(vrow << 11) + (bm & 2047) + sub] = w;
        }
    }
}

// ---------------------------------------------------------------------------
// Output-projection GEMM (fp32 out).  R13-exact: 64x128 dbuf + T2 swizzle.
__global__ __launch_bounds__(256, 3) void gemm_out(
    const unsigned short* __restrict__ A,
    const unsigned short* __restrict__ W,
    const float* __restrict__ bias,
    float* __restrict__ C)
{
    const int N = 1024, K = 1024;
    __shared__ unsigned short As[2][64 * 64];
    __shared__ unsigned short Bs[2][128 * 64];
    const int tid  = threadIdx.x;
    const int lane = tid & 63, wave = tid >> 6;
    const int l15 = lane & 15, l4 = lane >> 4;
    const int bm = blockIdx.y * 64, bn = blockIdx.x * 128;
    const int wr = wave >> 1, wc = wave & 1;
    const int swz = l15 & 7;

    f32x4 acc[2][4];
    #pragma unroll
    for (int i = 0; i < 2; ++i)
        #pragma unroll
        for (int j = 0; j < 4; ++j)
            #pragma unroll
            for (int e = 0; e < 4; ++e) acc[i][j][e] = 0.f;

    const int srow = lane >> 3;
    const int scol = ((lane & 7) ^ srow) * 8;

    auto stage = [&](int bf, int k0) {
        #pragma unroll
        for (int i = 0; i < 2; ++i) {
            const int c = wave * 2 + i;
            gload_lds16(A + (size_t)(bm + c * 8 + srow) * K + k0 + scol,
                        &As[bf][c * 512]);
        }
        #pragma unroll
        for (int i = 0; i < 4; ++i) {
            const int c = wave * 4 + i;
            gload_lds16(W + (size_t)(bn + c * 8 + srow) * K + k0 + scol,
                        &Bs[bf][c * 512]);
        }
    };

    stage(0, 0);
    __syncthreads();

    int bufi = 0;
    for (int k0 = 0; k0 < K; k0 += 64) {
        if (k0 + 64 < K) stage(bufi ^ 1, k0 + 64);
        #pragma unroll
        for (int kk = 0; kk < 2; ++kk) {
            short8 af[2], bf[4];
            const int ko = ((kk * 4 + l4) ^ swz) << 3;
            #pragma unroll
            for (int i = 0; i < 2; ++i)
                af[i] = *(const short8*)&As[bufi][(wr * 32 + i * 16 + l15) * 64 + ko];
            #pragma unroll
            for (int j = 0; j < 4; ++j)
                bf[j] = *(const short8*)&Bs[bufi][(wc * 64 + j * 16 + l15) * 64 + ko];
            #pragma unroll
            for (int i = 0; i < 2; ++i)
                #pragma unroll
                for (int j = 0; j < 4; ++j)
                    acc[i][j] = __builtin_amdgcn_mfma_f32_16x16x32_bf16(
                        af[i], bf[j], acc[i][j], 0, 0, 0);
        }
        __syncthreads();
        bufi ^= 1;
    }

    #pragma unroll
    for (int j = 0; j < 4; ++j) {
        const int col = bn + wc * 64 + j * 16 + l15;
        const float bj = bias[col];
        #pragma unroll
        for (int i = 0; i < 2; ++i) {
            const int row0 = bm + wr * 32 + i * 16 + l4 * 4;
            #pragma unroll
            for (int r = 0; r < 4; ++r)
                C[(size_t)(row0 + r) * N + col] = acc[i][j][r] + bj;
        }
    }
}

// ---------------------------------------------------------------------------
// Flash attention, R19-exact (best: 58.1us).  defer-max + branch-local
// shuffles; 8 waves, KVBLK=128 dbuf as two 64-halves, XCD-chunked.
__global__ __launch_bounds__(512, 4) void attn_fwd(
    const unsigned short* __restrict__ qp,
    const unsigned short* __restrict__ kp,
    const unsigned short* __restrict__ vt,
    unsigned short* __restrict__ op)
{
    __shared__ unsigned short Ks[2][128 * 64];  // [buf][kv 0..127][d] swizzled
    __shared__ unsigned short Vs[2][2][64 * 64];// [buf][half][d][kv]  swizzled
    __shared__ unsigned short P[8][16 * 64];    // [wave][q][kv]       swizzled

    const int tid = threadIdx.x;
    const int lane = tid & 63, wave = tid >> 6;  // wave 0..7
    const int l15 = lane & 15, l4 = lane >> 4;
    const int swz = (l15 & 7) << 3;             // XOR mask in short units

    // XCD-chunked block swizzle: 512 blocks, bijective (512%8==0)
    const int flat = blockIdx.x;
    const int swzb = (flat & 7) * 64 + (flat >> 3);
    const int bx = swzb & 15;                   // q-tile index (128 rows)
    const int bh = swzb >> 4;                   // batch*head
    const int b = bh >> 4, h = bh & 15;
    const int q0 = bx * 128 + wave * 16;

    const size_t xbase = (size_t)b * 2048 * 1024 + h * 64;   // qp/kp
    const size_t vbase = (size_t)bh * 64 * 2048;             // vt

    // staging source addressing (pre-swizzled global col, m173 pattern)
    const int sr = lane >> 3;                   // row within 8-row chunk
    const int sc = ((lane & 7) ^ sr) * 8;       // swizzled col (shorts)

    // Q as B-operand frags: col=q(l15), k=d
    short8 bq[2];
    #pragma unroll
    for (int kk = 0; kk < 2; ++kk)
        bq[kk] = *(const short8*)&qp[xbase
            + (size_t)(q0 + l15) * 1024 + kk * 32 + l4 * 8];

    f32x4 acc[4];                   // O^T: [dj]; row=d_local, col=q=l15
    #pragma unroll
    for (int dj = 0; dj < 4; ++dj)
        #pragma unroll
        for (int e = 0; e < 4; ++e) acc[dj][e] = 0.f;

    float m_run = -1e30f, l_part = 0.f;         // l lane-partial (16 kv/lane)

    // staging: K = 16 chunks (2/wave), V = 2 halves x 8 chunks (2/wave total)
    auto stage = [&](int bf, int kv0) {
        #pragma unroll
        for (int i = 0; i < 2; ++i) {
            const int c = wave * 2 + i;
            gload_lds16(kp + xbase + (size_t)(kv0 + c * 8 + sr) * 1024 + sc,
                        &Ks[bf][c * 512]);
        }
        #pragma unroll
        for (int h2 = 0; h2 < 2; ++h2)
            gload_lds16(vt + vbase + (size_t)(wave * 8 + sr) * 2048
                            + kv0 + h2 * 64 + sc,
                        &Vs[bf][h2][wave * 512]);
    };

    // ---- prologue: stage tile 0 into buf 0 ----
    stage(0, 0);
    __syncthreads();

    const int NT = 2048 / 128;
    int buf = 0;
    for (int t = 0; t < NT; ++t) {
        // ---- stage next 128-kv tile into buf^1 ----
        if (t + 1 < NT) stage(buf ^ 1, (t + 1) * 128);

        #pragma unroll
        for (int hh = 0; hh < 2; ++hh) {
            // ---- S^T = K Q^T for this 64-kv half ----
            f32x4 st[4];            // kv = hh*64 + j*16 + l4*4 + r ; q = l15
            {
                short8 ak[4];
                #pragma unroll
                for (int j = 0; j < 4; ++j)
                    ak[j] = *(const short8*)&Ks[buf][(hh * 64 + j * 16 + l15) * 64
                                                     + ((l4 << 3) ^ swz)];
                const f32x4 z4 = {0.f, 0.f, 0.f, 0.f};
                #pragma unroll
                for (int j = 0; j < 4; ++j)
                    st[j] = __builtin_amdgcn_mfma_f32_16x16x32_bf16(
                        ak[j], bq[0], z4, 0, 0, 0);
                #pragma unroll
                for (int j = 0; j < 4; ++j)
                    ak[j] = *(const short8*)&Ks[buf][(hh * 64 + j * 16 + l15) * 64
                                                     + (((4 + l4) << 3) ^ swz)];
                #pragma unroll
                for (int j = 0; j < 4; ++j)
                    st[j] = __builtin_amdgcn_mfma_f32_16x16x32_bf16(
                        ak[j], bq[1], st[j], 0, 0, 0);
            }

            // ---- prefetch V frags for this half ----
            short8 av[2][4];        // [kvc][dj]
            #pragma unroll
            for (int kvc = 0; kvc < 2; ++kvc)
                #pragma unroll
                for (int dj = 0; dj < 4; ++dj)
                    av[kvc][dj] = *(const short8*)&Vs[buf][hh]
                        [(dj * 16 + l15) * 64 + (((kvc * 4 + l4) << 3) ^ swz)];

            // ---- softmax (exp2 domain), defer-max, branch-local shuffles ----
            {
                float tm[4];
                #pragma unroll
                for (int j = 0; j < 4; ++j)
                    tm[j] = fmaxf(fmaxf(st[j][0], st[j][1]),
                                  fmaxf(st[j][2], st[j][3]));
                const float mxl = fmaxf(fmaxf(tm[0], tm[1]),
                                        fmaxf(tm[2], tm[3]));   // lane-local
                // row max <= m_run+8  iff  all 4 lanes' local maxima pass
                if (!__all(mxl - m_run <= 8.0f)) {
                    float mx = fmaxf(mxl, __shfl_xor(mxl, 16));
                    mx = fmaxf(mx, __shfl_xor(mx, 32));
                    const float mnew = fmaxf(m_run, mx);
                    const float corr = exp2_fast(m_run - mnew);
                    m_run = mnew;
                    l_part *= corr;
                    #pragma unroll
                    for (int dj = 0; dj < 4; ++dj) acc[dj] *= corr;
                }
                float ts[4];
                #pragma unroll
                for (int j = 0; j < 4; ++j) {
                    float p0 = exp2_fast(st[j][0] - m_run);
                    float p1 = exp2_fast(st[j][1] - m_run);
                    float p2 = exp2_fast(st[j][2] - m_run);
                    float p3 = exp2_fast(st[j][3] - m_run);
                    st[j][0] = p0; st[j][1] = p1;
                    st[j][2] = p2; st[j][3] = p3;
                    ts[j] = (p0 + p1) + (p2 + p3);
                }
                l_part += (ts[0] + ts[1]) + (ts[2] + ts[3]);
            }

            // ---- P^T -> swizzled per-wave LDS (b64 writes) ----
            #pragma unroll
            for (int j = 0; j < 4; ++j) {
                uint2v w;
                w.x = cvt_pk_bf16(st[j][0], st[j][1]);
                w.y = cvt_pk_bf16(st[j][2], st[j][3]);
                *(uint2v*)&P[wave][l15 * 64 + ((j * 16 + l4 * 4) ^ swz)] = w;
            }

            // ---- O^T += V^T P^T ----
            #pragma unroll
            for (int kvc = 0; kvc < 2; ++kvc) {
                short8 pb = *(const short8*)&P[wave][l15 * 64
                                                + (((kvc * 4 + l4) << 3) ^ swz)];
                #pragma unroll
                for (int dj = 0; dj < 4; ++dj)
                    acc[dj] = __builtin_amdgcn_mfma_f32_16x16x32_bf16(
                        av[kvc][dj], pb, acc[dj], 0, 0, 0);
            }
        }

        __syncthreads();            // drains vmcnt (staging done) + LDS reads
        buf ^= 1;
    }

    // ---- epilogue: reduce lane-partial l, divide, 8B vector stores ----
    {
        float l = l_part;
        l += __shfl_xor(l, 16);
        l += __shfl_xor(l, 32);
        const float inv = 1.0f / l;
        const int t = q0 + l15;
        #pragma unroll
        for (int dj = 0; dj < 4; ++dj) {
            uint2v w;
            w.x = cvt_pk_bf16(acc[dj][0] * inv, acc[dj][1] * inv);
            w.y = cvt_pk_bf16(acc[dj][2] * inv, acc[dj][3] * inv);
            *(uint2v*)&op[((size_t)(b * 2048 + t)) * 1024
                          + h * 64 + dj * 16 + l4 * 4] = w;
        }
    }
}

// ---------------------------------------------------------------------------
extern "C" void kernel_launch(void* const* d_in, const int* in_sizes, int n_in,
                              void* d_out, int out_size, void* d_ws, size_t ws_size,
                              hipStream_t stream)
{
    const float* q  = (const float*)d_in[0];
    const float* k  = (const float*)d_in[1];
    const float* v  = (const float*)d_in[2];
    const float* wq = (const float*)d_in[3];
    const float* bq = (const float*)d_in[4];
    const float* wk = (const float*)d_in[5];
    const float* bk = (const float*)d_in[6];
    const float* wv = (const float*)d_in[7];
    const float* bv = (const float*)d_in[8];
    const float* wo = (const float*)d_in[9];
    const float* bo = (const float*)d_in[10];
    float* out = (float*)d_out;

    const int M = 4096, N = 1024;
    unsigned char* ws = (unsigned char*)d_ws;
    const size_t SX = (size_t)M * 1024 * 2;     // 8 MB
    const size_t SW = (size_t)N * 1024 * 2;     // 2 MB
    unsigned short* xq  = (unsigned short*)(ws);
    unsigned short* xk  = (unsigned short*)(ws + SX);
    unsigned short* xv  = (unsigned short*)(ws + 2 * SX);
    unsigned short* wqb = (unsigned short*)(ws + 3 * SX);
    unsigned short* wkb = (unsigned short*)(ws + 3 * SX + SW);
    unsigned short* wvb = (unsigned short*)(ws + 3 * SX + 2 * SW);
    unsigned short* wob = (unsigned short*)(ws + 3 * SX + 3 * SW);
    unsigned short* qp  = (unsigned short*)(ws + 3 * SX + 4 * SW);
    unsigned short* kp  = qp + (size_t)M * N;
    unsigned short* vt  = kp + (size_t)M * N;
    unsigned short* opb = vt + (size_t)M * N;

    pack_all<<<dim3(16384), 256, 0, stream>>>(q, k, v, wq, wk, wv, wo,
                                              xq, xk, xv, wqb, wkb, wvb, wob);

    gemm_qkv<<<dim3(8, 32, 3), 256, 0, stream>>>(xq, xk, xv, wqb, wkb, wvb,
                                                 bq, bk, bv, qp, kp, vt);

    attn_fwd<<<dim3(512), 512, 0, stream>>>(qp, kp, vt, opb);

    gemm_out<<<dim3(8, 64), 256, 0, stream>>>(opb, wob, bo, out);
}

// Round 23
// 124.349 us; speedup vs baseline: 1.0181x; 1.0181x over previous
//
#include <hip/hip_runtime.h>
#include <math.h>

// ---------------------------------------------------------------------------
// MultiHeadAttention forward, MI355X/gfx950.  Round 23 = R21-exact (best
// verified: 124.66us).  R22's LDS-bounce epilogue was +1.9us -> reverted.
//   pack_all: fused fp32->bf16 (one launch, HBM roofline)
//   gemm_qkv: R13-exact 128x128 (256,2) + T2 swizzle (measured best)
//   gemm_out: R13-exact 64x128 dbuf + T2 swizzle
//   attn_fwd: R19-exact (58.1us: defer-max + branch-local shuffles,
//             8 waves, KVBLK=128 dbuf as two 64-halves, XCD-chunked)
// ---------------------------------------------------------------------------

typedef __attribute__((ext_vector_type(8))) short short8;     // 8 x bf16 frag
typedef __attribute__((ext_vector_type(4))) float f32x4;      // MFMA acc
typedef __attribute__((ext_vector_type(4))) float float4v;
typedef __attribute__((ext_vector_type(4))) unsigned short ushort4v;
typedef __attribute__((ext_vector_type(2))) unsigned int uint2v;

typedef __attribute__((address_space(3))) unsigned int lds_uint;
typedef __attribute__((address_space(1))) unsigned int glb_uint;

__device__ __forceinline__ void gload_lds16(const void* g, void* l) {
    __builtin_amdgcn_global_load_lds((glb_uint*)(unsigned long long)g,
                                     (lds_uint*)(unsigned int)(unsigned long long)l,
                                     16, 0, 0);
}

__device__ __forceinline__ unsigned short f32_bf16(float f) {
    union { float f; unsigned int u; } x; x.f = f;
    unsigned int r = x.u + 0x7fffu + ((x.u >> 16) & 1u);   // RNE
    return (unsigned short)(r >> 16);
}

__device__ __forceinline__ unsigned int cvt_pk_bf16(float lo, float hi) {
    unsigned int r;
    asm("v_cvt_pk_bf16_f32 %0, %1, %2" : "=v"(r) : "v"(lo), "v"(hi));
    return r;
}

// single-instruction exp2
__device__ __forceinline__ float exp2_fast(float x) {
    float r;
    asm("v_exp_f32 %0, %1" : "=v"(r) : "v"(x));
    return r;
}

// SCALE * log2(e): folded into Q projection so softmax runs in exp2 domain
#define QSCALE 0.18033688011112042f

// ---------------------------------------------------------------------------
// Fused pack: blocks 0..12287 -> q/k/v (4096 blocks each); blocks
// 12288..16383 -> wq/wk/wv/wo (1024 blocks each).
__global__ void pack_all(const float* __restrict__ q, const float* __restrict__ k,
                         const float* __restrict__ v,
                         const float* __restrict__ wq, const float* __restrict__ wk,
                         const float* __restrict__ wv, const float* __restrict__ wo,
                         unsigned short* __restrict__ oq, unsigned short* __restrict__ ok,
                         unsigned short* __restrict__ ov,
                         unsigned short* __restrict__ owq, unsigned short* __restrict__ owk,
                         unsigned short* __restrict__ owv, unsigned short* __restrict__ owo)
{
    const int blk = blockIdx.x;
    const float* in;
    unsigned short* out;
    int i;
    if (blk < 12288) {                       // q/k/v: 4096 blocks each
        const int sel = blk >> 12;           // 0,1,2
        in  = (sel == 0) ? q : (sel == 1) ? k : v;
        out = (sel == 0) ? oq : (sel == 1) ? ok : ov;
        i = ((blk & 4095) << 8) + threadIdx.x;
    } else {                                 // weights: 1024 blocks each
        const int wb = blk - 12288;
        const int sel = wb >> 10;            // 0..3
        in  = (sel == 0) ? wq : (sel == 1) ? wk : (sel == 2) ? wv : wo;
        out = (sel == 0) ? owq : (sel == 1) ? owk : (sel == 2) ? owv : owo;
        i = ((wb & 1023) << 8) + threadIdx.x;
    }
    float4v vv = ((const float4v*)in)[i];
    ushort4v o;
    o.x = f32_bf16(vv.x); o.y = f32_bf16(vv.y);
    o.z = f32_bf16(vv.z); o.w = f32_bf16(vv.w);
    ((ushort4v*)out)[i] = o;
}

// ---------------------------------------------------------------------------
// Batched QKV projection GEMM (R13-exact: 128x128, 4 waves, T2 swizzle).
__global__ __launch_bounds__(256, 2) void gemm_qkv(
    const unsigned short* __restrict__ A0, const unsigned short* __restrict__ A1,
    const unsigned short* __restrict__ A2,
    const unsigned short* __restrict__ W0, const unsigned short* __restrict__ W1,
    const unsigned short* __restrict__ W2,
    const float* __restrict__ bs0, const float* __restrict__ bs1,
    const float* __restrict__ bs2,
    unsigned short* __restrict__ O0, unsigned short* __restrict__ O1,
    unsigned short* __restrict__ O2)
{
    const int z = blockIdx.z;
    const unsigned short* A = (z == 0) ? A0 : (z == 1) ? A1 : A2;
    const unsigned short* W = (z == 0) ? W0 : (z == 1) ? W1 : W2;
    const float* bias        = (z == 0) ? bs0 : (z == 1) ? bs1 : bs2;
    unsigned short* C        = (z == 0) ? O0 : (z == 1) ? O1 : O2;
    const float oscale = (z == 0) ? QSCALE : 1.0f;
    const int N = 1024, K = 1024;

    __shared__ unsigned short As[128 * 64];
    __shared__ unsigned short Bs[128 * 64];
    const int tid  = threadIdx.x;
    const int lane = tid & 63, wave = tid >> 6;
    const int l15 = lane & 15, l4 = lane >> 4;
    const int bm = blockIdx.y * 128, bn = blockIdx.x * 128;
    const int wr = wave >> 1, wc = wave & 1;
    const int swz = l15 & 7;                    // XOR key (8-short units)

    f32x4 acc[4][4];
    #pragma unroll
    for (int i = 0; i < 4; ++i)
        #pragma unroll
        for (int j = 0; j < 4; ++j)
            #pragma unroll
            for (int e = 0; e < 4; ++e) acc[i][j][e] = 0.f;

    const int srow = lane >> 3;                 // row 0..7 within chunk
    const int scol = ((lane & 7) ^ srow) * 8;   // pre-swizzled source col

    for (int k0 = 0; k0 < K; k0 += 64) {
        __syncthreads();
        #pragma unroll
        for (int i = 0; i < 4; ++i) {
            int c = wave * 4 + i;
            int row = c * 8 + srow;
            gload_lds16(A + (size_t)(bm + row) * K + k0 + scol, &As[c * 512]);
            gload_lds16(W + (size_t)(bn + row) * K + k0 + scol, &Bs[c * 512]);
        }
        __syncthreads();
        #pragma unroll
        for (int kk = 0; kk < 2; ++kk) {
            short8 af[4], bf[4];
            const int ko = ((kk * 4 + l4) ^ swz) << 3;   // swizzled col
            #pragma unroll
            for (int i = 0; i < 4; ++i)
                af[i] = *(const short8*)&As[(wr * 64 + i * 16 + l15) * 64 + ko];
            #pragma unroll
            for (int j = 0; j < 4; ++j)
                bf[j] = *(const short8*)&Bs[(wc * 64 + j * 16 + l15) * 64 + ko];
            #pragma unroll
            for (int i = 0; i < 4; ++i)
                #pragma unroll
                for (int j = 0; j < 4; ++j)
                    acc[i][j] = __builtin_amdgcn_mfma_f32_16x16x32_bf16(
                        af[i], bf[j], acc[i][j], 0, 0, 0);
        }
    }

    #pragma unroll
    for (int j = 0; j < 4; ++j) {
        const int col = bn + wc * 64 + j * 16 + l15;
        const float bj = bias[col];
        #pragma unroll
        for (int i = 0; i < 4; ++i) {
            const int row0 = bm + wr * 64 + i * 16 + l4 * 4;
            #pragma unroll
            for (int r = 0; r < 4; ++r) {
                const int row = row0 + r;
                const float v = (acc[i][j][r] + bj) * oscale;
                if (z < 2) {
                    C[(size_t)row * N + col] = f32_bf16(v);
                } else {
                    const int b = row >> 11, t = row & 2047;
                    C[(((size_t)((b << 4) + (col >> 6)) * 64
                        + (col & 63)) << 11) + t] = f32_bf16(v);
                }
            }
        }
    }
}

// ---------------------------------------------------------------------------
// Output-projection GEMM (fp32 out).  R13-exact: 64x128 dbuf + T2 swizzle.
__global__ __launch_bounds__(256, 3) void gemm_out(
    const unsigned short* __restrict__ A,
    const unsigned short* __restrict__ W,
    const float* __restrict__ bias,
    float* __restrict__ C)
{
    const int N = 1024, K = 1024;
    __shared__ unsigned short As[2][64 * 64];
    __shared__ unsigned short Bs[2][128 * 64];
    const int tid  = threadIdx.x;
    const int lane = tid & 63, wave = tid >> 6;
    const int l15 = lane & 15, l4 = lane >> 4;
    const int bm = blockIdx.y * 64, bn = blockIdx.x * 128;
    const int wr = wave >> 1, wc = wave & 1;
    const int swz = l15 & 7;

    f32x4 acc[2][4];
    #pragma unroll
    for (int i = 0; i < 2; ++i)
        #pragma unroll
        for (int j = 0; j < 4; ++j)
            #pragma unroll
            for (int e = 0; e < 4; ++e) acc[i][j][e] = 0.f;

    const int srow = lane >> 3;
    const int scol = ((lane & 7) ^ srow) * 8;

    auto stage = [&](int bf, int k0) {
        #pragma unroll
        for (int i = 0; i < 2; ++i) {
            const int c = wave * 2 + i;
            gload_lds16(A + (size_t)(bm + c * 8 + srow) * K + k0 + scol,
                        &As[bf][c * 512]);
        }
        #pragma unroll
        for (int i = 0; i < 4; ++i) {
            const int c = wave * 4 + i;
            gload_lds16(W + (size_t)(bn + c * 8 + srow) * K + k0 + scol,
                        &Bs[bf][c * 512]);
        }
    };

    stage(0, 0);
    __syncthreads();

    int bufi = 0;
    for (int k0 = 0; k0 < K; k0 += 64) {
        if (k0 + 64 < K) stage(bufi ^ 1, k0 + 64);
        #pragma unroll
        for (int kk = 0; kk < 2; ++kk) {
            short8 af[2], bf[4];
            const int ko = ((kk * 4 + l4) ^ swz) << 3;
            #pragma unroll
            for (int i = 0; i < 2; ++i)
                af[i] = *(const short8*)&As[bufi][(wr * 32 + i * 16 + l15) * 64 + ko];
            #pragma unroll
            for (int j = 0; j < 4; ++j)
                bf[j] = *(const short8*)&Bs[bufi][(wc * 64 + j * 16 + l15) * 64 + ko];
            #pragma unroll
            for (int i = 0; i < 2; ++i)
                #pragma unroll
                for (int j = 0; j < 4; ++j)
                    acc[i][j] = __builtin_amdgcn_mfma_f32_16x16x32_bf16(
                        af[i], bf[j], acc[i][j], 0, 0, 0);
        }
        __syncthreads();
        bufi ^= 1;
    }

    #pragma unroll
    for (int j = 0; j < 4; ++j) {
        const int col = bn + wc * 64 + j * 16 + l15;
        const float bj = bias[col];
        #pragma unroll
        for (int i = 0; i < 2; ++i) {
            const int row0 = bm + wr * 32 + i * 16 + l4 * 4;
            #pragma unroll
            for (int r = 0; r < 4; ++r)
                C[(size_t)(row0 + r) * N + col] = acc[i][j][r] + bj;
        }
    }
}

// ---------------------------------------------------------------------------
// Flash attention, R19-exact (best: 58.1us).  defer-max + branch-local
// shuffles; 8 waves, KVBLK=128 dbuf as two 64-halves, XCD-chunked.
__global__ __launch_bounds__(512, 4) void attn_fwd(
    const unsigned short* __restrict__ qp,
    const unsigned short* __restrict__ kp,
    const unsigned short* __restrict__ vt,
    unsigned short* __restrict__ op)
{
    __shared__ unsigned short Ks[2][128 * 64];  // [buf][kv 0..127][d] swizzled
    __shared__ unsigned short Vs[2][2][64 * 64];// [buf][half][d][kv]  swizzled
    __shared__ unsigned short P[8][16 * 64];    // [wave][q][kv]       swizzled

    const int tid = threadIdx.x;
    const int lane = tid & 63, wave = tid >> 6;  // wave 0..7
    const int l15 = lane & 15, l4 = lane >> 4;
    const int swz = (l15 & 7) << 3;             // XOR mask in short units

    // XCD-chunked block swizzle: 512 blocks, bijective (512%8==0)
    const int flat = blockIdx.x;
    const int swzb = (flat & 7) * 64 + (flat >> 3);
    const int bx = swzb & 15;                   // q-tile index (128 rows)
    const int bh = swzb >> 4;                   // batch*head
    const int b = bh >> 4, h = bh & 15;
    const int q0 = bx * 128 + wave * 16;

    const size_t xbase = (size_t)b * 2048 * 1024 + h * 64;   // qp/kp
    const size_t vbase = (size_t)bh * 64 * 2048;             // vt

    // staging source addressing (pre-swizzled global col, m173 pattern)
    const int sr = lane >> 3;                   // row within 8-row chunk
    const int sc = ((lane & 7) ^ sr) * 8;       // swizzled col (shorts)

    // Q as B-operand frags: col=q(l15), k=d
    short8 bq[2];
    #pragma unroll
    for (int kk = 0; kk < 2; ++kk)
        bq[kk] = *(const short8*)&qp[xbase
            + (size_t)(q0 + l15) * 1024 + kk * 32 + l4 * 8];

    f32x4 acc[4];                   // O^T: [dj]; row=d_local, col=q=l15
    #pragma unroll
    for (int dj = 0; dj < 4; ++dj)
        #pragma unroll
        for (int e = 0; e < 4; ++e) acc[dj][e] = 0.f;

    float m_run = -1e30f, l_part = 0.f;         // l lane-partial (16 kv/lane)

    // staging: K = 16 chunks (2/wave), V = 2 halves x 8 chunks (2/wave total)
    auto stage = [&](int bf, int kv0) {
        #pragma unroll
        for (int i = 0; i < 2; ++i) {
            const int c = wave * 2 + i;
            gload_lds16(kp + xbase + (size_t)(kv0 + c * 8 + sr) * 1024 + sc,
                        &Ks[bf][c * 512]);
        }
        #pragma unroll
        for (int h2 = 0; h2 < 2; ++h2)
            gload_lds16(vt + vbase + (size_t)(wave * 8 + sr) * 2048
                            + kv0 + h2 * 64 + sc,
                        &Vs[bf][h2][wave * 512]);
    };

    // ---- prologue: stage tile 0 into buf 0 ----
    stage(0, 0);
    __syncthreads();

    const int NT = 2048 / 128;
    int buf = 0;
    for (int t = 0; t < NT; ++t) {
        // ---- stage next 128-kv tile into buf^1 ----
        if (t + 1 < NT) stage(buf ^ 1, (t + 1) * 128);

        #pragma unroll
        for (int hh = 0; hh < 2; ++hh) {
            // ---- S^T = K Q^T for this 64-kv half ----
            f32x4 st[4];            // kv = hh*64 + j*16 + l4*4 + r ; q = l15
            {
                short8 ak[4];
                #pragma unroll
                for (int j = 0; j < 4; ++j)
                    ak[j] = *(const short8*)&Ks[buf][(hh * 64 + j * 16 + l15) * 64
                                                     + ((l4 << 3) ^ swz)];
                const f32x4 z4 = {0.f, 0.f, 0.f, 0.f};
                #pragma unroll
                for (int j = 0; j < 4; ++j)
                    st[j] = __builtin_amdgcn_mfma_f32_16x16x32_bf16(
                        ak[j], bq[0], z4, 0, 0, 0);
                #pragma unroll
                for (int j = 0; j < 4; ++j)
                    ak[j] = *(const short8*)&Ks[buf][(hh * 64 + j * 16 + l15) * 64
                                                     + (((4 + l4) << 3) ^ swz)];
                #pragma unroll
                for (int j = 0; j < 4; ++j)
                    st[j] = __builtin_amdgcn_mfma_f32_16x16x32_bf16(
                        ak[j], bq[1], st[j], 0, 0, 0);
            }

            // ---- prefetch V frags for this half ----
            short8 av[2][4];        // [kvc][dj]
            #pragma unroll
            for (int kvc = 0; kvc < 2; ++kvc)
                #pragma unroll
                for (int dj = 0; dj < 4; ++dj)
                    av[kvc][dj] = *(const short8*)&Vs[buf][hh]
                        [(dj * 16 + l15) * 64 + (((kvc * 4 + l4) << 3) ^ swz)];

            // ---- softmax (exp2 domain), defer-max, branch-local shuffles ----
            {
                float tm[4];
                #pragma unroll
                for (int j = 0; j < 4; ++j)
                    tm[j] = fmaxf(fmaxf(st[j][0], st[j][1]),
                                  fmaxf(st[j][2], st[j][3]));
                const float mxl = fmaxf(fmaxf(tm[0], tm[1]),
                                        fmaxf(tm[2], tm[3]));   // lane-local
                // row max <= m_run+8  iff  all 4 lanes' local maxima pass
                if (!__all(mxl - m_run <= 8.0f)) {
                    float mx = fmaxf(mxl, __shfl_xor(mxl, 16));
                    mx = fmaxf(mx, __shfl_xor(mx, 32));
                    const float mnew = fmaxf(m_run, mx);
                    const float corr = exp2_fast(m_run - mnew);
                    m_run = mnew;
                    l_part *= corr;
                    #pragma unroll
                    for (int dj = 0; dj < 4; ++dj) acc[dj] *= corr;
                }
                float ts[4];
                #pragma unroll
                for (int j = 0; j < 4; ++j) {
                    float p0 = exp2_fast(st[j][0] - m_run);
                    float p1 = exp2_fast(st[j][1] - m_run);
                    float p2 = exp2_fast(st[j][2] - m_run);
                    float p3 = exp2_fast(st[j][3] - m_run);
                    st[j][0] = p0; st[j][1] = p1;
                    st[j][2] = p2; st[j][3] = p3;
                    ts[j] = (p0 + p1) + (p2 + p3);
                }
                l_part += (ts[0] + ts[1]) + (ts[2] + ts[3]);
            }

            // ---- P^T -> swizzled per-wave LDS (b64 writes) ----
            #pragma unroll
            for (int j = 0; j < 4; ++j) {
                uint2v w;
                w.x = cvt_pk_bf16(st[j][0], st[j][1]);
                w.y = cvt_pk_bf16(st[j][2], st[j][3]);
                *(uint2v*)&P[wave][l15 * 64 + ((j * 16 + l4 * 4) ^ swz)] = w;
            }

            // ---- O^T += V^T P^T ----
            #pragma unroll
            for (int kvc = 0; kvc < 2; ++kvc) {
                short8 pb = *(const short8*)&P[wave][l15 * 64
                                                + (((kvc * 4 + l4) << 3) ^ swz)];
                #pragma unroll
                for (int dj = 0; dj < 4; ++dj)
                    acc[dj] = __builtin_amdgcn_mfma_f32_16x16x32_bf16(
                        av[kvc][dj], pb, acc[dj], 0, 0, 0);
            }
        }

        __syncthreads();            // drains vmcnt (staging done) + LDS reads
        buf ^= 1;
    }

    // ---- epilogue: reduce lane-partial l, divide, 8B vector stores ----
    {
        float l = l_part;
        l += __shfl_xor(l, 16);
        l += __shfl_xor(l, 32);
        const float inv = 1.0f / l;
        const int t = q0 + l15;
        #pragma unroll
        for (int dj = 0; dj < 4; ++dj) {
            uint2v w;
            w.x = cvt_pk_bf16(acc[dj][0] * inv, acc[dj][1] * inv);
            w.y = cvt_pk_bf16(acc[dj][2] * inv, acc[dj][3] * inv);
            *(uint2v*)&op[((size_t)(b * 2048 + t)) * 1024
                          + h * 64 + dj * 16 + l4 * 4] = w;
        }
    }
}

// ---------------------------------------------------------------------------
extern "C" void kernel_launch(void* const* d_in, const int* in_sizes, int n_in,
                              void* d_out, int out_size, void* d_ws, size_t ws_size,
                              hipStream_t stream)
{
    const float* q  = (const float*)d_in[0];
    const float* k  = (const float*)d_in[1];
    const float* v  = (const float*)d_in[2];
    const float* wq = (const float*)d_in[3];
    const float* bq = (const float*)d_in[4];
    const float* wk = (const float*)d_in[5];
    const float* bk = (const float*)d_in[6];
    const float* wv = (const float*)d_in[7];
    const float* bv = (const float*)d_in[8];
    const float* wo = (const float*)d_in[9];
    const float* bo = (const float*)d_in[10];
    float* out = (float*)d_out;

    const int M = 4096, N = 1024;
    unsigned char* ws = (unsigned char*)d_ws;
    const size_t SX = (size_t)M * 1024 * 2;     // 8 MB
    const size_t SW = (size_t)N * 1024 * 2;     // 2 MB
    unsigned short* xq  = (unsigned short*)(ws);
    unsigned short* xk  = (unsigned short*)(ws + SX);
    unsigned short* xv  = (unsigned short*)(ws + 2 * SX);
    unsigned short* wqb = (unsigned short*)(ws + 3 * SX);
    unsigned short* wkb = (unsigned short*)(ws + 3 * SX + SW);
    unsigned short* wvb = (unsigned short*)(ws + 3 * SX + 2 * SW);
    unsigned short* wob = (unsigned short*)(ws + 3 * SX + 3 * SW);
    unsigned short* qp  = (unsigned short*)(ws + 3 * SX + 4 * SW);
    unsigned short* kp  = qp + (size_t)M * N;
    unsigned short* vt  = kp + (size_t)M * N;
    unsigned short* opb = vt + (size_t)M * N;

    pack_all<<<dim3(16384), 256, 0, stream>>>(q, k, v, wq, wk, wv, wo,
                                              xq, xk, xv, wqb, wkb, wvb, wob);

    gemm_qkv<<<dim3(8, 32, 3), 256, 0, stream>>>(xq, xk, xv, wqb, wkb, wvb,
                                                 bq, bk, bv, qp, kp, vt);

    attn_fwd<<<dim3(512), 512, 0, stream>>>(qp, kp, vt, opb);

    gemm_out<<<dim3(8, 64), 256, 0, stream>>>(opb, wob, bo, out);
}